// Round 1
// baseline (70.983 us; speedup 1.0000x reference)
//
#include <hip/hip_runtime.h>

#define IM 64
#define NPIX (3 * IM * IM)          // 12288 floats per sample
#define NQ   (NPIX / 4)             // 3072 float4 per sample
#define BLK  256
#define QPT  (NQ / BLK)             // 12 float4 per thread

constexpr float LOG_2PI = 1.8378770664093453f;
constexpr float OBS_CONST = -((float)NPIX) * 0.5f * LOG_2PI;  // -11291.9...

__device__ __forceinline__ float sigmoidf_(float x) {
    return 1.0f / (1.0f + __expf(-x));
}
__device__ __forceinline__ float softplusf_(float x) {
    return logf(1.0f + __expf(x));
}

__global__ __launch_bounds__(BLK) void GenerativeModel_25821343384066_kernel(
    const float* __restrict__ latent,
    const float* __restrict__ obs,
    const float* __restrict__ raw_size,
    const float* __restrict__ raw_color,
    const float* __restrict__ raw_cs,
    const float* __restrict__ raw_blur,
    float* __restrict__ out)
{
    const int i = blockIdx.x;      // sample index 0..8191
    const int t = threadIdx.x;     // 0..255

    __shared__ float fxs[IM];      // x-factor of occ
    __shared__ float fys[IM];      // y-factor of occ
    __shared__ float gs[3 * IM];   // fy[y] * color[c], indexed c*64+y
    __shared__ float wsum[BLK / 64];

    if (t < 2 * IM) {
        const float size = sigmoidf_(raw_size[0]);
        const float k = softplusf_(raw_cs[0]) / (softplusf_(raw_blur[0]) + 0.001f);
        if (t < IM) {
            const float mx = sigmoidf_(latent[i]) * (1.0f - size);
            const float gx = ((float)t + 0.5f) * (1.0f / IM);
            fxs[t] = sigmoidf_(k * (gx - mx)) * sigmoidf_(k * (mx + size - gx));
        } else {
            const int y = t - IM;
            const float gy = 1.0f - ((float)y + 0.5f) * (1.0f / IM);
            fys[y] = sigmoidf_(k * gy) * sigmoidf_(k * (size - gy));
        }
    }
    __syncthreads();
    if (t < 3 * IM) {
        gs[t] = fys[t & (IM - 1)] * sigmoidf_(raw_color[t >> 6]);
    }
    __syncthreads();

    // Per-thread x positions are loop-invariant: q = t + j*256, and 256 % 16 == 0
    // (16 float4 per image row), so x = 4*(t & 15) for all j.
    const int x0 = (t & 15) * 4;
    const float fx0 = fxs[x0 + 0];
    const float fx1 = fxs[x0 + 1];
    const float fx2 = fxs[x0 + 2];
    const float fx3 = fxs[x0 + 3];

    const float4* __restrict__ obs4 =
        reinterpret_cast<const float4*>(obs + (size_t)i * NPIX);

    float acc = 0.0f;
    #pragma unroll
    for (int j = 0; j < QPT; ++j) {
        const int q = t + j * BLK;           // float4 index in [0, 3072)
        const float4 v = obs4[q];
        // q = c*1024 + y*16 + x/4  ->  q>>4 = c*64 + y
        const float oy = gs[q >> 4];         // 16-lane-uniform broadcast read
        const float z0 = v.x - fx0 * oy;
        const float z1 = v.y - fx1 * oy;
        const float z2 = v.z - fx2 * oy;
        const float z3 = v.w - fx3 * oy;
        acc += z0 * z0 + z1 * z1 + z2 * z2 + z3 * z3;
    }

    // wave-64 butterfly reduction
    #pragma unroll
    for (int off = 32; off > 0; off >>= 1)
        acc += __shfl_down(acc, off, 64);
    if ((t & 63) == 0) wsum[t >> 6] = acc;
    __syncthreads();
    if (t == 0) {
        float s = 0.0f;
        #pragma unroll
        for (int w = 0; w < BLK / 64; ++w) s += wsum[w];
        const float lat = latent[i];
        const float latent_lp = -0.5f * lat * lat - 0.5f * LOG_2PI;
        out[i] = latent_lp - 0.5f * s + OBS_CONST;
    }
}

extern "C" void kernel_launch(void* const* d_in, const int* in_sizes, int n_in,
                              void* d_out, int out_size, void* d_ws, size_t ws_size,
                              hipStream_t stream) {
    const float* latent    = (const float*)d_in[0];
    const float* obs       = (const float*)d_in[1];
    const float* raw_size  = (const float*)d_in[2];
    const float* raw_color = (const float*)d_in[3];
    const float* raw_cs    = (const float*)d_in[4];
    const float* raw_blur  = (const float*)d_in[5];
    float* out = (float*)d_out;

    const int n = in_sizes[0];   // 8192 samples
    GenerativeModel_25821343384066_kernel<<<n, BLK, 0, stream>>>(
        latent, obs, raw_size, raw_color, raw_cs, raw_blur, out);
}

// Round 3
// 62.781 us; speedup vs baseline: 1.1306x; 1.1306x over previous
//
#include <hip/hip_runtime.h>

#define IM 64
#define NPIX (3 * IM * IM)          // 12288 floats per sample
#define NQ   (NPIX / 4)             // 3072 float4 per sample
#define BLK  256
#define QPT  (NQ / BLK)             // 12 float4 per thread

typedef float vfloat4 __attribute__((ext_vector_type(4)));

constexpr float LOG_2PI = 1.8378770664093453f;
constexpr float OBS_CONST = -((float)NPIX) * 0.5f * LOG_2PI;

__device__ __forceinline__ float sigmoidf_(float x) {
    return 1.0f / (1.0f + __expf(-x));
}
__device__ __forceinline__ float softplusf_(float x) {
    return logf(1.0f + __expf(x));
}

__global__ __launch_bounds__(BLK) void GenerativeModel_25821343384066_kernel(
    const float* __restrict__ latent,
    const float* __restrict__ obs,
    const float* __restrict__ raw_size,
    const float* __restrict__ raw_color,
    const float* __restrict__ raw_cs,
    const float* __restrict__ raw_blur,
    float* __restrict__ out)
{
    const int i = blockIdx.x;      // sample index 0..8191
    const int t = threadIdx.x;     // 0..255

    __shared__ float fxs[IM];      // x-factor of occ
    __shared__ float fys[IM];      // y-factor of occ
    __shared__ float gs[3 * IM];   // fy[y] * color[c], indexed c*64+y
    __shared__ float wsum[BLK / 64];

    if (t < 2 * IM) {
        const float size = sigmoidf_(raw_size[0]);
        const float k = softplusf_(raw_cs[0]) / (softplusf_(raw_blur[0]) + 0.001f);
        if (t < IM) {
            const float mx = sigmoidf_(latent[i]) * (1.0f - size);
            const float gx = ((float)t + 0.5f) * (1.0f / IM);
            fxs[t] = sigmoidf_(k * (gx - mx)) * sigmoidf_(k * (mx + size - gx));
        } else {
            const int y = t - IM;
            const float gy = 1.0f - ((float)y + 0.5f) * (1.0f / IM);
            fys[y] = sigmoidf_(k * gy) * sigmoidf_(k * (size - gy));
        }
    }
    __syncthreads();
    if (t < 3 * IM) {
        gs[t] = fys[t & (IM - 1)] * sigmoidf_(raw_color[t >> 6]);
    }
    __syncthreads();

    // Per-thread x positions are loop-invariant: q = t + j*256, 256 % 16 == 0.
    const int x0 = (t & 15) * 4;
    const float fx0 = fxs[x0 + 0];
    const float fx1 = fxs[x0 + 1];
    const float fx2 = fxs[x0 + 2];
    const float fx3 = fxs[x0 + 3];

    // Hoist the 12 per-iteration gs broadcasts into registers:
    // (t + j*256) >> 4 == (t>>4) + 16*j  (loop-invariant index pattern).
    float g[QPT];
    #pragma unroll
    for (int j = 0; j < QPT; ++j) g[j] = gs[(t >> 4) + 16 * j];

    const vfloat4* __restrict__ obs4 =
        reinterpret_cast<const vfloat4*>(obs + (size_t)i * NPIX);

    float acc0 = 0.0f, acc1 = 0.0f;
    #pragma unroll
    for (int j = 0; j < QPT; ++j) {
        const vfloat4 v = __builtin_nontemporal_load(&obs4[t + j * BLK]);
        const float oy = g[j];
        const float z0 = v.x - fx0 * oy;
        const float z1 = v.y - fx1 * oy;
        const float z2 = v.z - fx2 * oy;
        const float z3 = v.w - fx3 * oy;
        if (j & 1) acc1 += z0 * z0 + z1 * z1 + z2 * z2 + z3 * z3;
        else       acc0 += z0 * z0 + z1 * z1 + z2 * z2 + z3 * z3;
    }
    float acc = acc0 + acc1;

    // wave-64 butterfly reduction
    #pragma unroll
    for (int off = 32; off > 0; off >>= 1)
        acc += __shfl_down(acc, off, 64);
    if ((t & 63) == 0) wsum[t >> 6] = acc;
    __syncthreads();
    if (t == 0) {
        float s = 0.0f;
        #pragma unroll
        for (int w = 0; w < BLK / 64; ++w) s += wsum[w];
        const float lat = latent[i];
        const float latent_lp = -0.5f * lat * lat - 0.5f * LOG_2PI;
        out[i] = latent_lp - 0.5f * s + OBS_CONST;
    }
}

extern "C" void kernel_launch(void* const* d_in, const int* in_sizes, int n_in,
                              void* d_out, int out_size, void* d_ws, size_t ws_size,
                              hipStream_t stream) {
    const float* latent    = (const float*)d_in[0];
    const float* obs       = (const float*)d_in[1];
    const float* raw_size  = (const float*)d_in[2];
    const float* raw_color = (const float*)d_in[3];
    const float* raw_cs    = (const float*)d_in[4];
    const float* raw_blur  = (const float*)d_in[5];
    float* out = (float*)d_out;

    const int n = in_sizes[0];   // 8192 samples
    GenerativeModel_25821343384066_kernel<<<n, BLK, 0, stream>>>(
        latent, obs, raw_size, raw_color, raw_cs, raw_blur, out);
}